// Round 9
// baseline (281.934 us; speedup 1.0000x reference)
//
#include <hip/hip_runtime.h>

#define KSIZE 7
#define NEG_INF (-1e30f)
#define IMG_H 512
#define IMG_W 512
#define STRIPE 32              // output rows per wave

// <2 x float> — fadd lowers to v_pk_add_f32 (VOP3P)
typedef float pk2 __attribute__((ext_vector_type(2)));

// fmaxf(a, fmaxf(b, c)) -> v_max3_f32
#define M3(a, b, c) fmaxf((a), fmaxf((b), (c)))

static __device__ __forceinline__ pk2 mk2(float a, float b) {
    pk2 r; r.x = a; r.y = b; return r;
}

// One filter-row contribution: taps t_j = v[1+l+j] + f[j]. Max tree exactly
// equal in value to the scalar form (max associative/commutative).
static __device__ __forceinline__ float dil_body(float acc, pk2 a, pk2 b, pk2 c,
                                                 float t6v, pk2 f01, pk2 f23,
                                                 pk2 f45, float f6) {
    const pk2 t01 = a + f01;          // v_pk_add_f32
    const pk2 t23 = b + f23;
    const pk2 t45 = c + f45;
    const float t6 = t6v + f6;
    const float u = M3(t01.x, t01.y, t23.x);
    const float w = M3(t23.y, t45.x, t45.y);
    const float z = M3(acc, t6, u);
    return fmaxf(z, w);
}

// No LDS, no barriers, no staging: pure VMEM->VALU rolling-accumulator walk.
// Each wave owns a 256-col x 32-row stripe; lane owns 4 cols. Per input row:
// 3 guarded float4 loads (wave's 3 loads hit the SAME cache lines -> L1 serves
// the horizontal halo; vertical halo rows come from L2/L3). Register window
// W[2] double-buffers a 1-row prefetch (static indices only — rule #20).
__global__ __launch_bounds__(256)
void GrayscaleDilation2D_kernel(const float* __restrict__ img,
                                const float* __restrict__ filt,
                                float* __restrict__ out) {
    const int lane = threadIdx.x;                 // 0..63
    const int wy   = threadIdx.y;                 // 0..3
    const int x0 = (wy & 1) * 256;                // column half
    const int y0 = (blockIdx.y * 2 + (wy >> 1)) * STRIPE;
    const int plane = blockIdx.z;
    const float* __restrict__ src = img + (size_t)plane * IMG_H * IMG_W;
    float* __restrict__ dst       = out + (size_t)plane * IMG_H * IMG_W;

    const int c0 = x0 + lane * 4;                 // output col base (mult of 4)
    const bool okA = (c0 != 0);                   // left halo chunk in-bounds?
    const bool okC = (c0 + 4 < IMG_W);            // right halo chunk in-bounds?

    // Filter prepacked as pairs + scalar; uniform const-index loads -> SGPRs.
    pk2 fp[KSIZE][3];
    float f6[KSIZE];
#pragma unroll
    for (int i = 0; i < KSIZE; ++i) {
        const float* fr = filt + i * KSIZE;
        fp[i][0] = mk2(fr[0], fr[1]);
        fp[i][1] = mk2(fr[2], fr[3]);
        fp[i][2] = mk2(fr[4], fr[5]);
        f6[i] = fr[6];
    }

    const float4 NI4 = make_float4(NEG_INF, NEG_INF, NEG_INF, NEG_INF);
    float4 W[2][3];    // [buf][chunk]: chunks cover cols c0-4..c0+7 of one row

    // Load input row j (gy = y0-3+j) into buffer D (static buf at call sites).
    auto loadrow = [&](int j, float4 (&D)[3]) {
        const int gy = y0 - 3 + j;
        float4 A = NI4, B = NI4, C = NI4;
        if ((unsigned)gy < IMG_H) {               // wave-uniform guard
            const float* rp = src + (size_t)gy * IMG_W + (c0 - 4);
            if (okA) A = *(const float4*)(rp);
            B = *(const float4*)(rp + 4);         // always in-bounds
            if (okC) C = *(const float4*)(rp + 8);
        }
        D[0] = A; D[1] = B; D[2] = C;
    };

    // Rolling accumulators: acc slot s holds output row yo with yo%8 == s.
    // Slot algebra verbatim from R5 (3x harness-verified, absmax 0.0).
    float acc[8][4];
#pragma unroll
    for (int a = 0; a < 8; ++a)
#pragma unroll
        for (int l = 0; l < 4; ++l) acc[a][l] = NEG_INF;

    loadrow(0, W[0]);                             // prologue prefetch

    // One step: consume row j (buf U&1), prefetch row j+1 (buf (U+1)&1).
    // LAST = no prefetch. All acc/W indices compile-time after unroll.
#define ROW_STEP(U, MBASE, LAST)                                              \
    {                                                                         \
        const int j = (MBASE) + (U);                                          \
        if (!(LAST)) loadrow(j + 1, W[((U) + 1) & 1]);                        \
        const float4 A = W[(U) & 1][0];                                       \
        const float4 B = W[(U) & 1][1];                                       \
        const float4 C = W[(U) & 1][2];                                       \
        const pk2 e0 = mk2(A.x, A.y), e1 = mk2(A.z, A.w);                     \
        const pk2 e2 = mk2(B.x, B.y), e3 = mk2(B.z, B.w);                     \
        const pk2 e4 = mk2(C.x, C.y);                                         \
        const float v10 = C.z;                                                \
        const pk2 q0 = mk2(A.y, A.z), q1 = mk2(A.w, B.x);                     \
        const pk2 q2 = mk2(B.y, B.z), q3 = mk2(B.w, C.x);                     \
        _Pragma("unroll")                                                     \
        for (int i = 0; i < KSIZE; ++i) {                                     \
            const int a = ((U) - i) & 7;                                      \
            acc[a][0] = dil_body(acc[a][0], q0, q1, q2, e3.y,                 \
                                 fp[i][0], fp[i][1], fp[i][2], f6[i]);        \
            acc[a][1] = dil_body(acc[a][1], e1, e2, e3, e4.x,                 \
                                 fp[i][0], fp[i][1], fp[i][2], f6[i]);        \
            acc[a][2] = dil_body(acc[a][2], q1, q2, q3, e4.y,                 \
                                 fp[i][0], fp[i][1], fp[i][2], f6[i]);        \
            acc[a][3] = dil_body(acc[a][3], e2, e3, e4, v10,                  \
                                 fp[i][0], fp[i][1], fp[i][2], f6[i]);        \
        }                                                                     \
        const int sret = ((U) + 2) & 7;                                       \
        if (j >= 6 && j <= 37) {   /* retire output row yo = y0 + j - 6 */    \
            const int yo = y0 - 6 + j;                                        \
            float4 res = make_float4(acc[sret][0], acc[sret][1],              \
                                     acc[sret][2], acc[sret][3]);             \
            *(float4*)&dst[(size_t)yo * IMG_W + c0] = res;                    \
        }                                                                     \
        _Pragma("unroll")                                                     \
        for (int l = 0; l < 4; ++l) acc[sret][l] = NEG_INF;                   \
    }

    // Main: 4 chunks of 8 steps (j = 0..31). The 2-buffer W forces the
    // compiler to keep loads exactly 1 row ahead (WAR self-limiting).
#pragma unroll 1
    for (int m = 0; m < 4; ++m) {
        const int mb = m * 8;
        ROW_STEP(0, mb, false) ROW_STEP(1, mb, false)
        ROW_STEP(2, mb, false) ROW_STEP(3, mb, false)
        ROW_STEP(4, mb, false) ROW_STEP(5, mb, false)
        ROW_STEP(6, mb, false) ROW_STEP(7, mb, false)
    }
    // Tail: j = 32..37 (last load at step 36 fetches row 37 = gy y0+34).
    ROW_STEP(0, 32, false) ROW_STEP(1, 32, false) ROW_STEP(2, 32, false)
    ROW_STEP(3, 32, false) ROW_STEP(4, 32, false) ROW_STEP(5, 32, true)
#undef ROW_STEP
}

extern "C" void kernel_launch(void* const* d_in, const int* in_sizes, int n_in,
                              void* d_out, int out_size, void* d_ws, size_t ws_size,
                              hipStream_t stream) {
    const float* img  = (const float*)d_in[0];
    const float* filt = (const float*)d_in[1];
    float* out = (float*)d_out;

    const int planes = in_sizes[0] / (IMG_H * IMG_W);   // B*C = 128
    dim3 grid(1, IMG_H / (STRIPE * 2), planes);         // 1 x 8 x 128 = 1024 WGs
    dim3 block(64, 4);   // 4 independent waves: 2 col-halves x 2 stripes
    hipLaunchKernelGGL(GrayscaleDilation2D_kernel, grid, block, 0, stream,
                       img, filt, out);
}